// Round 13
// baseline (258.398 us; speedup 1.0000x reference)
//
#include <hip/hip_runtime.h>
#include <stdint.h>

// CONV-KNRM fused pipeline for MI355X (gfx950). Round 13 (diagnostic):
//  - k_pool split into TWO half-grid dispatches (b 0-15, b 16-31) so its
//    profile passes stop crowding k_project out of the top-5: k_project's
//    true duration has been UNMEASURED since R3; ~100us of the total is
//    unaccounted. Math/body byte-identical to R12 (best: 235.9us).
//  - k_project/k_convert/k_qvec/k_finale unchanged from R12.
// B=32, Q=16, D=4096, V=30000, C=128, EM=300, NBINS=11.

typedef short short8 __attribute__((ext_vector_type(8)));
typedef unsigned short ushort8 __attribute__((ext_vector_type(8)));
typedef float floatx4 __attribute__((ext_vector_type(4)));

#define NB_V 30000

__device__ __forceinline__ unsigned short f32_bf16(float f) {
  union { float f; uint32_t u; } v; v.f = f;
  return (unsigned short)((v.u + 0x7FFFu + ((v.u >> 16) & 1u)) >> 16);
}
// rounded bf16 of f, returned as f32 bit-pattern (bf16 in high half)
__device__ __forceinline__ uint32_t rnd_hi(float f) {
  union { float f; uint32_t u; } v; v.f = f;
  return (v.u + 0x7FFFu + ((v.u >> 16) & 1u)) & 0xFFFF0000u;
}
__device__ __forceinline__ float bits_f32(uint32_t u) {
  union { uint32_t u; float f; } v; v.u = u; return v.f;
}
__device__ __forceinline__ float bflo(uint32_t u) { return bits_f32(u << 16); }
__device__ __forceinline__ float bfhi(uint32_t u) { return bits_f32(u & 0xFFFF0000u); }

// ------------- wv -> bf16 (30080x320, zero-padded) + W -> bf16 -------------
__global__ __launch_bounds__(256) void k_convert(
    const float* __restrict__ wv,
    const float* __restrict__ Wu, const float* __restrict__ Wb,
    const float* __restrict__ Wt,
    unsigned short* __restrict__ wv_bf, unsigned short* __restrict__ W_bf) {
  int t = blockIdx.x * 256 + threadIdx.x;
  if (t < 30080 * 40) {
    int row = t / 40, kc = (t % 40) * 8;
    ushort8 o;
    if (row < NB_V && kc + 8 <= 300) {
      const float* p = wv + (size_t)row * 300 + kc;
      float4 a = *(const float4*)p, b = *(const float4*)(p + 4);
      o[0] = f32_bf16(a.x); o[1] = f32_bf16(a.y); o[2] = f32_bf16(a.z); o[3] = f32_bf16(a.w);
      o[4] = f32_bf16(b.x); o[5] = f32_bf16(b.y); o[6] = f32_bf16(b.z); o[7] = f32_bf16(b.w);
    } else if (row < NB_V) {
#pragma unroll
      for (int e = 0; e < 8; e++)
        o[e] = (kc + e < 300) ? f32_bf16(wv[(size_t)row * 300 + kc + e]) : (unsigned short)0;
    } else {
#pragma unroll
      for (int e = 0; e < 8; e++) o[e] = 0;
    }
    *(ushort8*)(wv_bf + (size_t)row * 320 + kc) = o;
  } else {
    int u = t - 30080 * 40;
    if (u >= 768 * 40) return;
    int chg = u / 40, kc = u % 40;
    int seg = chg >> 7, ch = chg & 127;
    const float* Wsrc; int kw, jj;
    if (seg == 0)      { Wsrc = Wu; kw = 1; jj = 0; }
    else if (seg <= 2) { Wsrc = Wb; kw = 2; jj = seg - 1; }
    else               { Wsrc = Wt; kw = 3; jj = seg - 3; }
    const float* src = Wsrc + ((size_t)ch * kw + jj) * 300;
    int k0 = kc * 8;
    ushort8 o;
#pragma unroll
    for (int e = 0; e < 8; e++)
      o[e] = (k0 + e < 300) ? f32_bf16(src[k0 + e]) : (unsigned short)0;
    *(ushort8*)(W_bf + (size_t)chg * 320 + k0) = o;
  }
}

// ---------------- Stage A: vocab projection GEMM (R3 structure) ----------------
// grid = 235*6; seg = bid%6 (6 consecutive blocks share A rows in L2).
// 128 rows x 128 cols, K=320. LDS: 64ch x 328-stride (41,984B -> 3 blocks/CU).
// A: full-K register cache (80 VGPR) loaded BEFORE staging. W re-staged per
// 64-col half from W_bf (uint4 copies; row = 41 16B-chunks).
__global__ __launch_bounds__(256) void k_project(
    const unsigned short* __restrict__ wv_bf,
    const unsigned short* __restrict__ W_bf,
    unsigned short* __restrict__ P) {
  __shared__ __align__(16) unsigned short wlds[64 * 328];   // 41,984 B
  int tid = threadIdx.x;
  int bid = blockIdx.x;
  int mb = bid / 6, seg = bid % 6;
  int wave = tid >> 6, lane = tid & 63;
  int li = lane & 15, quad = lane >> 4;
  int rows0 = mb * 128 + wave * 32;

  // A-fragment register cache: both 16-row tiles, all 10 K-steps (80 VGPRs)
  short8 af[2][10];
  const unsigned short* abase = wv_bf + (size_t)(rows0 + li) * 320 + quad * 8;
#pragma unroll
  for (int ks = 0; ks < 10; ks++) {
    af[0][ks] = *(const short8*)(abase + ks * 32);
    af[1][ks] = *(const short8*)(abase + 16 * 320 + ks * 32);
  }
  const unsigned short* wseg = W_bf + (size_t)seg * 128 * 320;

  for (int h = 0; h < 2; h++) {
    if (h) __syncthreads();   // prev half's MFMA reads done before restage
    {  // stage 64 channels x 320 K from W_bf (uint4; dest row stride 41 chunks)
#pragma unroll
      for (int i = 0; i < 10; i++) {
        int idx = i * 256 + tid;        // source chunk 0..2559
        int ch = idx / 40, kc = idx - ch * 40;
        uint4 v = *(const uint4*)(wseg + (size_t)(h * 64 + ch) * 320 + kc * 8);
        *(uint4*)(wlds + (ch * 41 + kc) * 8) = v;
      }
    }
    __syncthreads();

    floatx4 acc[2][4];
#pragma unroll
    for (int rt = 0; rt < 2; rt++)
#pragma unroll
      for (int ct = 0; ct < 4; ct++) acc[rt][ct] = (floatx4){0.f, 0.f, 0.f, 0.f};

#pragma unroll
    for (int ks = 0; ks < 10; ks++) {
      int ck = ks * 32 + quad * 8;
#pragma unroll
      for (int ct = 0; ct < 4; ct++) {
        short8 bf = *(const short8*)&wlds[(ct * 16 + li) * 328 + ck];
        acc[0][ct] = __builtin_amdgcn_mfma_f32_16x16x32_bf16(af[0][ks], bf, acc[0][ct], 0, 0, 0);
        acc[1][ct] = __builtin_amdgcn_mfma_f32_16x16x32_bf16(af[1][ks], bf, acc[1][ct], 0, 0, 0);
      }
    }
#pragma unroll
    for (int rt = 0; rt < 2; rt++)
#pragma unroll
      for (int ct = 0; ct < 4; ct++)
#pragma unroll
        for (int r = 0; r < 4; r++) {
          int row = rows0 + rt * 16 + quad * 4 + r;   // < 30080, P padded
          P[(size_t)row * 768 + seg * 128 + h * 64 + ct * 16 + li] =
              f32_bf16(acc[rt][ct][r]);
        }
  }
}

// ---------------- query n-gram vectors (tiny: 384 waves) ----------------
template <int KK>
__device__ __forceinline__ void build_qvec4(
    int b, int type, int l0,
    const int* __restrict__ tokens, const unsigned short* __restrict__ P,
    const float* __restrict__ bias,
    unsigned short* __restrict__ vec, float* __restrict__ inv, int lane) {
  const int segBase[3] = {0, 128, 384};
  int sub = lane >> 4, li = lane & 15;
  int l = l0 + sub;
  size_t row = (size_t)(b * 3 + type) * 16 + l;
  uint4 o = make_uint4(0u, 0u, 0u, 0u);
  float invv = 0.0f;
  if (l + KK <= 16) {
    float v[8];
    {
      float4 b0 = *(const float4*)(bias + li * 8);
      float4 b1 = *(const float4*)(bias + li * 8 + 4);
      v[0] = b0.x; v[1] = b0.y; v[2] = b0.z; v[3] = b0.w;
      v[4] = b1.x; v[5] = b1.y; v[6] = b1.z; v[7] = b1.w;
    }
    const int* tk = tokens + (size_t)b * 16 + l;
    const unsigned short* pb = P + segBase[type] + li * 8;
#pragma unroll
    for (int j = 0; j < KK; j++) {
      uint4 pp = *(const uint4*)(pb + (size_t)tk[j] * 768 + j * 128);
      v[0] += bflo(pp.x); v[1] += bfhi(pp.x);
      v[2] += bflo(pp.y); v[3] += bfhi(pp.y);
      v[4] += bflo(pp.z); v[5] += bfhi(pp.z);
      v[6] += bflo(pp.w); v[7] += bfhi(pp.w);
    }
    uint32_t w[4];
    float s = 0.0f;
#pragma unroll
    for (int e = 0; e < 4; e++) {
      float f0 = fmaxf(v[2 * e], 0.0f) + 1e-9f;
      float f1 = fmaxf(v[2 * e + 1], 0.0f) + 1e-9f;
      uint32_t h0 = rnd_hi(f0), h1 = rnd_hi(f1);
      w[e] = (h0 >> 16) | h1;
      float g0 = bits_f32(h0), g1 = bits_f32(h1);
      s = fmaf(g0, g0, fmaf(g1, g1, s));
    }
#pragma unroll
    for (int off = 1; off < 16; off <<= 1) s += __shfl_xor(s, off);
    invv = rsqrtf(s);
    o = make_uint4(w[0], w[1], w[2], w[3]);
  }
  *(uint4*)(vec + row * 128 + li * 8) = o;
  if (li == 0) inv[row] = invv;
}

__global__ __launch_bounds__(256) void k_qvec(
    const int* __restrict__ qtok, const unsigned short* __restrict__ P,
    const float* __restrict__ bu, const float* __restrict__ bb,
    const float* __restrict__ bt,
    unsigned short* __restrict__ qvec, float* __restrict__ qinv) {
  int wid = blockIdx.x * 4 + (threadIdx.x >> 6);  // 0..383
  int lane = threadIdx.x & 63;
  int b = wid / 12;
  int rem = wid % 12;
  int type = rem / 4, l0 = (rem % 4) * 4;
  if (type == 0)      build_qvec4<1>(b, 0, l0, qtok, P, bu, qvec, qinv, lane);
  else if (type == 1) build_qvec4<2>(b, 1, l0, qtok, P, bb, qvec, qinv, lane);
  else                build_qvec4<3>(b, 2, l0, qtok, P, bt, qvec, qinv, lane);
}

// ------- Stage C: fused doc-build-in-registers + sim MFMA + pooling -------
// grid = 16 b * 3 dt * 32 chunks per dispatch (2 dispatches). R7/R12 body.
template <int KK>
__device__ __forceinline__ void pool_body(
    int b, int chunk, const int* __restrict__ dtok,
    const unsigned short* __restrict__ P, const float* __restrict__ bias,
    const unsigned short* qlds, const float* qil, float* pacc,
    float* __restrict__ pout, int tid) {
  constexpr int dt = KK - 1;
  constexpr int segB = (dt == 0) ? 0 : (dt == 1) ? 128 : 384;
  const int wave = tid >> 6, lane = tid & 63;
  const int li = lane & 15, quad = lane >> 4;
  const int validD = 4096 - dt;

  float accb[3][11];
#pragma unroll
  for (int qt = 0; qt < 3; qt++)
#pragma unroll
    for (int i = 0; i < 11; i++) accb[qt][i] = 0.f;

  for (int grp = wave; grp < 8; grp += 4) {
    int d0 = chunk * 128 + grp * 16;
    int mydoc = d0 + li;                 // this lane builds doc `mydoc`
    bool ok = (mydoc + KK <= 4096);
    int tox[KK];
#pragma unroll
    for (int j = 0; j < KK; j++) {
      int ti = mydoc + j; if (ti > 4095) ti = 4095;   // clamp: value unused if !ok
      tox[j] = dtok[(size_t)b * 4096 + ti];
    }
    float sq = 0.f;
    short8 af[4];
#pragma unroll
    for (int sl = 0; sl < 4; sl++) {
      int co = sl * 32 + quad * 8;       // channel offset within segment
      float4 bA = *(const float4*)(bias + co);
      float4 bB = *(const float4*)(bias + co + 4);
      float v[8] = {bA.x, bA.y, bA.z, bA.w, bB.x, bB.y, bB.z, bB.w};
#pragma unroll
      for (int j = 0; j < KK; j++) {
        uint4 pp = *(const uint4*)(P + (size_t)tox[j] * 768 + segB + co);
        v[0] += bflo(pp.x); v[1] += bfhi(pp.x);
        v[2] += bflo(pp.y); v[3] += bfhi(pp.y);
        v[4] += bflo(pp.z); v[5] += bfhi(pp.z);
        v[6] += bflo(pp.w); v[7] += bfhi(pp.w);
      }
      union { uint32_t u[4]; short8 s8; } pk;
#pragma unroll
      for (int e = 0; e < 4; e++) {
        float f0 = fmaxf(v[2 * e], 0.0f) + 1e-9f;
        float f1 = fmaxf(v[2 * e + 1], 0.0f) + 1e-9f;
        uint32_t h0 = rnd_hi(f0), h1 = rnd_hi(f1);
        pk.u[e] = (h0 >> 16) | h1;
        float g0 = bits_f32(h0), g1 = bits_f32(h1);
        sq = fmaf(g0, g0, fmaf(g1, g1, sq));
      }
      af[sl] = pk.s8;   // garbage rows are masked by validD below
    }
    sq += __shfl_xor(sq, 16);           // reduce over quads (same doc)
    sq += __shfl_xor(sq, 32);
    float invd = ok ? rsqrtf(sq) : 0.0f;
    float iv[4];
#pragma unroll
    for (int r = 0; r < 4; r++) iv[r] = __shfl(invd, quad * 4 + r);

#pragma unroll
    for (int qt = 0; qt < 3; qt++) {
      floatx4 sim = (floatx4){0.f, 0.f, 0.f, 0.f};
      const unsigned short* qb = qlds + (qt * 16 + li) * 136 + quad * 8;
      sim = __builtin_amdgcn_mfma_f32_16x16x32_bf16(af[0], *(const short8*)(qb), sim, 0, 0, 0);
      sim = __builtin_amdgcn_mfma_f32_16x16x32_bf16(af[1], *(const short8*)(qb + 32), sim, 0, 0, 0);
      sim = __builtin_amdgcn_mfma_f32_16x16x32_bf16(af[2], *(const short8*)(qb + 64), sim, 0, 0, 0);
      sim = __builtin_amdgcn_mfma_f32_16x16x32_bf16(af[3], *(const short8*)(qb + 96), sim, 0, 0, 0);
      float invq = qil[qt * 16 + li];
#pragma unroll
      for (int r = 0; r < 4; r++) {
        if (d0 + quad * 4 + r < validD) {
          float s = sim[r] * (invq * iv[r]);
          // bin 0 (sigma=0.001): exp underflows to 0 unless s ~ 1
          if (s > 0.9868f) {
            float t0 = s - 1.0f;
            accb[qt][0] += __expf(t0 * t0 * -500000.0f);
          }
          // bins 1..10 (sigma=0.1, mu=0.9..-0.9): geometric recurrence
          float y = s - 0.9f;
          float f = __expf(y * y * -50.0f);
          float v = __expf(fmaf(y, -20.0f, -2.0f));
#pragma unroll
          for (int i = 1; i < 11; i++) {
            accb[qt][i] += f;
            f *= v;
            v *= 0.01831563889f;   // e^-4
          }
        }
      }
    }
  }
#pragma unroll
  for (int qt = 0; qt < 3; qt++) {
#pragma unroll
    for (int i = 0; i < 11; i++) {
      float v = accb[qt][i];
      v += __shfl_xor(v, 16);
      v += __shfl_xor(v, 32);
      if (lane < 16) pacc[wave * 528 + (qt * 16 + lane) * 11 + i] = v;
    }
  }
  __syncthreads();
  for (int idx = tid; idx < 528; idx += 256)
    pout[idx] = pacc[idx] + pacc[528 + idx] + pacc[1056 + idx] + pacc[1584 + idx];
}

__global__ __launch_bounds__(256, 4) void k_pool(
    const int* __restrict__ dtok,
    const unsigned short* __restrict__ P,
    const float* __restrict__ bu, const float* __restrict__ bb,
    const float* __restrict__ bt,
    const unsigned short* __restrict__ qvec, const float* __restrict__ qinv,
    float* __restrict__ partial, int b0) {
  __shared__ __align__(16) unsigned short qlds[48 * 136];   // 13,056 B
  __shared__ float qil[48];
  __shared__ float pacc[4 * 528];                           // 8,448 B
  int bid = blockIdx.x;
  int b = b0 + bid / 96, rem = bid % 96;
  int dt = rem / 32, chunk = rem % 32;
  int tid = threadIdx.x;
  for (int idx = tid; idx < 48 * 32; idx += 256) {
    int row = idx >> 5, kq = (idx & 31) * 4;
    *(uint2*)&qlds[row * 136 + kq] =
        *(const uint2*)(qvec + ((size_t)b * 48 + row) * 128 + kq);
  }
  if (tid < 48) qil[tid] = qinv[b * 48 + tid];
  __syncthreads();
  float* pout = partial + ((size_t)b * 96 + rem) * 528;
  if (dt == 0)      pool_body<1>(b, chunk, dtok, P, bu, qlds, qil, pacc, pout, tid);
  else if (dt == 1) pool_body<2>(b, chunk, dtok, P, bb, qlds, qil, pacc, pout, tid);
  else              pool_body<3>(b, chunk, dtok, P, bt, qlds, qil, pacc, pout, tid);
}

// ------- fused chunk-reduce + log + query-sum epilogue (one dispatch) -------
__global__ __launch_bounds__(256) void k_finale(const float* __restrict__ partial,
                                                float* __restrict__ out) {
  int idx = blockIdx.x * 256 + threadIdx.x;   // 50688 total
  if (idx >= 32 * 3 * 3 * 11 * 16) return;
  int q = idx & 15;
  int g = idx >> 4;                 // (b,qt,dt,bin), bin fastest
  int bin = g % 11; g /= 11;
  int dt = g % 3; g /= 3;
  int qt = g % 3; int b = g / 3;
  const float* p = partial + ((size_t)(b * 3 + dt) * 32) * 528 + (qt * 16 + q) * 11 + bin;
  float s = 0.f;
#pragma unroll
  for (int c = 0; c < 32; c++) s += p[c * 528];
  float t = (q < 16 - qt) ? 0.01f * logf(fmaxf(s, 1e-10f)) : 0.0f;
#pragma unroll
  for (int off = 1; off < 16; off <<= 1) t += __shfl_xor(t, off);
  if (q == 0) {
    const int p_of[3][3] = {{0, 2, 1}, {3, 5, 6}, {4, 7, 8}};
    out[b * 99 + p_of[qt][dt] * 11 + bin] = t;
  }
}

extern "C" void kernel_launch(void* const* d_in, const int* in_sizes, int n_in,
                              void* d_out, int out_size, void* d_ws, size_t ws_size,
                              hipStream_t stream) {
  const int* qtok = (const int*)d_in[0];
  const int* dtok = (const int*)d_in[1];
  // d_in[2] = batch_semantic: unused by the reference
  const float* wv = (const float*)d_in[3];
  const float* Wu = (const float*)d_in[4];
  const float* bu = (const float*)d_in[5];
  const float* Wb = (const float*)d_in[6];
  const float* bb = (const float*)d_in[7];
  const float* Wt = (const float*)d_in[8];
  const float* bt = (const float*)d_in[9];
  float* out = (float*)d_out;

  // workspace layout (bytes), footprint 148,838,400:
  //   P:       [0, 46,202,880)           30080*768*2   (live: project..pool)
  //   wv_bf:   [46,202,880, 65,454,080)  30080*320*2   (dead after project)
  //   W_bf:    [146,374,656, 146,866,176) 768*320*2    (dead after project)
  //   qvec:    [148,439,040, 148,832,256)
  //   qinv:    [148,832,256, 148,838,400)
  //   partial: [46,202,880, 52,690,944)  3072*528*4    (aliases wv_bf; written
  //            by k_pool after wv_bf is dead)
  char* ws = (char*)d_ws;
  unsigned short* P     = (unsigned short*)(ws);
  unsigned short* wv_bf = (unsigned short*)(ws + 46202880);
  unsigned short* W_bf  = (unsigned short*)(ws + 146374656);
  unsigned short* qvec  = (unsigned short*)(ws + 148439040);
  float* qinv           = (float*)(ws + 148832256);
  float* partial        = (float*)(ws + 46202880);

  k_convert<<<4820, 256, 0, stream>>>(wv, Wu, Wb, Wt, wv_bf, W_bf);
  k_project<<<235 * 6, 256, 0, stream>>>(wv_bf, W_bf, P);
  k_qvec<<<96, 256, 0, stream>>>(qtok, P, bu, bb, bt, qvec, qinv);
  k_pool<<<16 * 96, 256, 0, stream>>>(dtok, P, bu, bb, bt, qvec, qinv, partial, 0);
  k_pool<<<16 * 96, 256, 0, stream>>>(dtok, P, bu, bb, bt, qvec, qinv, partial, 16);
  k_finale<<<198, 256, 0, stream>>>(partial, out);
}

// Round 14
// 231.832 us; speedup vs baseline: 1.1146x; 1.1146x over previous
//
#include <hip/hip_runtime.h>
#include <stdint.h>

// CONV-KNRM fused pipeline for MI355X (gfx950). Round 14 = R12 (best, 235.9us)
// + ONE change: LPT dispatch order in k_pool (all heavy dt=2/KK=3 blocks
// first, then dt=1, then dt=0) so light blocks backfill the tail. R13's
// split showed k_project <= 66us (not the hidden whale) and cost +22us; the
// remaining k_pool lever is dt-imbalance tail at 29-38% occupancy.
// B=32, Q=16, D=4096, V=30000, C=128, EM=300, NBINS=11.

typedef short short8 __attribute__((ext_vector_type(8)));
typedef unsigned short ushort8 __attribute__((ext_vector_type(8)));
typedef float floatx4 __attribute__((ext_vector_type(4)));

#define NB_V 30000

__device__ __forceinline__ unsigned short f32_bf16(float f) {
  union { float f; uint32_t u; } v; v.f = f;
  return (unsigned short)((v.u + 0x7FFFu + ((v.u >> 16) & 1u)) >> 16);
}
// rounded bf16 of f, returned as f32 bit-pattern (bf16 in high half)
__device__ __forceinline__ uint32_t rnd_hi(float f) {
  union { float f; uint32_t u; } v; v.f = f;
  return (v.u + 0x7FFFu + ((v.u >> 16) & 1u)) & 0xFFFF0000u;
}
__device__ __forceinline__ float bits_f32(uint32_t u) {
  union { uint32_t u; float f; } v; v.u = u; return v.f;
}
__device__ __forceinline__ float bflo(uint32_t u) { return bits_f32(u << 16); }
__device__ __forceinline__ float bfhi(uint32_t u) { return bits_f32(u & 0xFFFF0000u); }

// ------------- wv -> bf16 (30080x320, zero-padded) + W -> bf16 -------------
__global__ __launch_bounds__(256) void k_convert(
    const float* __restrict__ wv,
    const float* __restrict__ Wu, const float* __restrict__ Wb,
    const float* __restrict__ Wt,
    unsigned short* __restrict__ wv_bf, unsigned short* __restrict__ W_bf) {
  int t = blockIdx.x * 256 + threadIdx.x;
  if (t < 30080 * 40) {
    int row = t / 40, kc = (t % 40) * 8;
    ushort8 o;
    if (row < NB_V && kc + 8 <= 300) {
      const float* p = wv + (size_t)row * 300 + kc;
      float4 a = *(const float4*)p, b = *(const float4*)(p + 4);
      o[0] = f32_bf16(a.x); o[1] = f32_bf16(a.y); o[2] = f32_bf16(a.z); o[3] = f32_bf16(a.w);
      o[4] = f32_bf16(b.x); o[5] = f32_bf16(b.y); o[6] = f32_bf16(b.z); o[7] = f32_bf16(b.w);
    } else if (row < NB_V) {
#pragma unroll
      for (int e = 0; e < 8; e++)
        o[e] = (kc + e < 300) ? f32_bf16(wv[(size_t)row * 300 + kc + e]) : (unsigned short)0;
    } else {
#pragma unroll
      for (int e = 0; e < 8; e++) o[e] = 0;
    }
    *(ushort8*)(wv_bf + (size_t)row * 320 + kc) = o;
  } else {
    int u = t - 30080 * 40;
    if (u >= 768 * 40) return;
    int chg = u / 40, kc = u % 40;
    int seg = chg >> 7, ch = chg & 127;
    const float* Wsrc; int kw, jj;
    if (seg == 0)      { Wsrc = Wu; kw = 1; jj = 0; }
    else if (seg <= 2) { Wsrc = Wb; kw = 2; jj = seg - 1; }
    else               { Wsrc = Wt; kw = 3; jj = seg - 3; }
    const float* src = Wsrc + ((size_t)ch * kw + jj) * 300;
    int k0 = kc * 8;
    ushort8 o;
#pragma unroll
    for (int e = 0; e < 8; e++)
      o[e] = (k0 + e < 300) ? f32_bf16(src[k0 + e]) : (unsigned short)0;
    *(ushort8*)(W_bf + (size_t)chg * 320 + k0) = o;
  }
}

// ---------------- Stage A: vocab projection GEMM (R3 structure) ----------------
// grid = 235*6; seg = bid%6 (6 consecutive blocks share A rows in L2).
// 128 rows x 128 cols, K=320. LDS: 64ch x 328-stride (41,984B -> 3 blocks/CU).
// A: full-K register cache (80 VGPR) loaded BEFORE staging. W re-staged per
// 64-col half from W_bf (uint4 copies; row = 41 16B-chunks).
__global__ __launch_bounds__(256) void k_project(
    const unsigned short* __restrict__ wv_bf,
    const unsigned short* __restrict__ W_bf,
    unsigned short* __restrict__ P) {
  __shared__ __align__(16) unsigned short wlds[64 * 328];   // 41,984 B
  int tid = threadIdx.x;
  int bid = blockIdx.x;
  int mb = bid / 6, seg = bid % 6;
  int wave = tid >> 6, lane = tid & 63;
  int li = lane & 15, quad = lane >> 4;
  int rows0 = mb * 128 + wave * 32;

  // A-fragment register cache: both 16-row tiles, all 10 K-steps (80 VGPRs)
  short8 af[2][10];
  const unsigned short* abase = wv_bf + (size_t)(rows0 + li) * 320 + quad * 8;
#pragma unroll
  for (int ks = 0; ks < 10; ks++) {
    af[0][ks] = *(const short8*)(abase + ks * 32);
    af[1][ks] = *(const short8*)(abase + 16 * 320 + ks * 32);
  }
  const unsigned short* wseg = W_bf + (size_t)seg * 128 * 320;

  for (int h = 0; h < 2; h++) {
    if (h) __syncthreads();   // prev half's MFMA reads done before restage
    {  // stage 64 channels x 320 K from W_bf (uint4; dest row stride 41 chunks)
#pragma unroll
      for (int i = 0; i < 10; i++) {
        int idx = i * 256 + tid;        // source chunk 0..2559
        int ch = idx / 40, kc = idx - ch * 40;
        uint4 v = *(const uint4*)(wseg + (size_t)(h * 64 + ch) * 320 + kc * 8);
        *(uint4*)(wlds + (ch * 41 + kc) * 8) = v;
      }
    }
    __syncthreads();

    floatx4 acc[2][4];
#pragma unroll
    for (int rt = 0; rt < 2; rt++)
#pragma unroll
      for (int ct = 0; ct < 4; ct++) acc[rt][ct] = (floatx4){0.f, 0.f, 0.f, 0.f};

#pragma unroll
    for (int ks = 0; ks < 10; ks++) {
      int ck = ks * 32 + quad * 8;
#pragma unroll
      for (int ct = 0; ct < 4; ct++) {
        short8 bf = *(const short8*)&wlds[(ct * 16 + li) * 328 + ck];
        acc[0][ct] = __builtin_amdgcn_mfma_f32_16x16x32_bf16(af[0][ks], bf, acc[0][ct], 0, 0, 0);
        acc[1][ct] = __builtin_amdgcn_mfma_f32_16x16x32_bf16(af[1][ks], bf, acc[1][ct], 0, 0, 0);
      }
    }
#pragma unroll
    for (int rt = 0; rt < 2; rt++)
#pragma unroll
      for (int ct = 0; ct < 4; ct++)
#pragma unroll
        for (int r = 0; r < 4; r++) {
          int row = rows0 + rt * 16 + quad * 4 + r;   // < 30080, P padded
          P[(size_t)row * 768 + seg * 128 + h * 64 + ct * 16 + li] =
              f32_bf16(acc[rt][ct][r]);
        }
  }
}

// ---------------- query n-gram vectors (tiny: 384 waves) ----------------
template <int KK>
__device__ __forceinline__ void build_qvec4(
    int b, int type, int l0,
    const int* __restrict__ tokens, const unsigned short* __restrict__ P,
    const float* __restrict__ bias,
    unsigned short* __restrict__ vec, float* __restrict__ inv, int lane) {
  const int segBase[3] = {0, 128, 384};
  int sub = lane >> 4, li = lane & 15;
  int l = l0 + sub;
  size_t row = (size_t)(b * 3 + type) * 16 + l;
  uint4 o = make_uint4(0u, 0u, 0u, 0u);
  float invv = 0.0f;
  if (l + KK <= 16) {
    float v[8];
    {
      float4 b0 = *(const float4*)(bias + li * 8);
      float4 b1 = *(const float4*)(bias + li * 8 + 4);
      v[0] = b0.x; v[1] = b0.y; v[2] = b0.z; v[3] = b0.w;
      v[4] = b1.x; v[5] = b1.y; v[6] = b1.z; v[7] = b1.w;
    }
    const int* tk = tokens + (size_t)b * 16 + l;
    const unsigned short* pb = P + segBase[type] + li * 8;
#pragma unroll
    for (int j = 0; j < KK; j++) {
      uint4 pp = *(const uint4*)(pb + (size_t)tk[j] * 768 + j * 128);
      v[0] += bflo(pp.x); v[1] += bfhi(pp.x);
      v[2] += bflo(pp.y); v[3] += bfhi(pp.y);
      v[4] += bflo(pp.z); v[5] += bfhi(pp.z);
      v[6] += bflo(pp.w); v[7] += bfhi(pp.w);
    }
    uint32_t w[4];
    float s = 0.0f;
#pragma unroll
    for (int e = 0; e < 4; e++) {
      float f0 = fmaxf(v[2 * e], 0.0f) + 1e-9f;
      float f1 = fmaxf(v[2 * e + 1], 0.0f) + 1e-9f;
      uint32_t h0 = rnd_hi(f0), h1 = rnd_hi(f1);
      w[e] = (h0 >> 16) | h1;
      float g0 = bits_f32(h0), g1 = bits_f32(h1);
      s = fmaf(g0, g0, fmaf(g1, g1, s));
    }
#pragma unroll
    for (int off = 1; off < 16; off <<= 1) s += __shfl_xor(s, off);
    invv = rsqrtf(s);
    o = make_uint4(w[0], w[1], w[2], w[3]);
  }
  *(uint4*)(vec + row * 128 + li * 8) = o;
  if (li == 0) inv[row] = invv;
}

__global__ __launch_bounds__(256) void k_qvec(
    const int* __restrict__ qtok, const unsigned short* __restrict__ P,
    const float* __restrict__ bu, const float* __restrict__ bb,
    const float* __restrict__ bt,
    unsigned short* __restrict__ qvec, float* __restrict__ qinv) {
  int wid = blockIdx.x * 4 + (threadIdx.x >> 6);  // 0..383
  int lane = threadIdx.x & 63;
  int b = wid / 12;
  int rem = wid % 12;
  int type = rem / 4, l0 = (rem % 4) * 4;
  if (type == 0)      build_qvec4<1>(b, 0, l0, qtok, P, bu, qvec, qinv, lane);
  else if (type == 1) build_qvec4<2>(b, 1, l0, qtok, P, bb, qvec, qinv, lane);
  else                build_qvec4<3>(b, 2, l0, qtok, P, bt, qvec, qinv, lane);
}

// ------- Stage C: fused doc-build-in-registers + sim MFMA + pooling -------
// LPT grid: bid/1024 -> dt=2,1,0 (heavy first); within: b = (bid%1024)/32,
// chunk = bid%32. partial layout unchanged: [(b*3+dt)*32+chunk][528].
template <int KK>
__device__ __forceinline__ void pool_body(
    int b, int chunk, const int* __restrict__ dtok,
    const unsigned short* __restrict__ P, const float* __restrict__ bias,
    const unsigned short* qlds, const float* qil, float* pacc,
    float* __restrict__ pout, int tid) {
  constexpr int dt = KK - 1;
  constexpr int segB = (dt == 0) ? 0 : (dt == 1) ? 128 : 384;
  const int wave = tid >> 6, lane = tid & 63;
  const int li = lane & 15, quad = lane >> 4;
  const int validD = 4096 - dt;

  float accb[3][11];
#pragma unroll
  for (int qt = 0; qt < 3; qt++)
#pragma unroll
    for (int i = 0; i < 11; i++) accb[qt][i] = 0.f;

  for (int grp = wave; grp < 8; grp += 4) {
    int d0 = chunk * 128 + grp * 16;
    int mydoc = d0 + li;                 // this lane builds doc `mydoc`
    bool ok = (mydoc + KK <= 4096);
    int tox[KK];
#pragma unroll
    for (int j = 0; j < KK; j++) {
      int ti = mydoc + j; if (ti > 4095) ti = 4095;   // clamp: value unused if !ok
      tox[j] = dtok[(size_t)b * 4096 + ti];
    }
    float sq = 0.f;
    short8 af[4];
#pragma unroll
    for (int sl = 0; sl < 4; sl++) {
      int co = sl * 32 + quad * 8;       // channel offset within segment
      float4 bA = *(const float4*)(bias + co);
      float4 bB = *(const float4*)(bias + co + 4);
      float v[8] = {bA.x, bA.y, bA.z, bA.w, bB.x, bB.y, bB.z, bB.w};
#pragma unroll
      for (int j = 0; j < KK; j++) {
        uint4 pp = *(const uint4*)(P + (size_t)tox[j] * 768 + segB + co);
        v[0] += bflo(pp.x); v[1] += bfhi(pp.x);
        v[2] += bflo(pp.y); v[3] += bfhi(pp.y);
        v[4] += bflo(pp.z); v[5] += bfhi(pp.z);
        v[6] += bflo(pp.w); v[7] += bfhi(pp.w);
      }
      union { uint32_t u[4]; short8 s8; } pk;
#pragma unroll
      for (int e = 0; e < 4; e++) {
        float f0 = fmaxf(v[2 * e], 0.0f) + 1e-9f;
        float f1 = fmaxf(v[2 * e + 1], 0.0f) + 1e-9f;
        uint32_t h0 = rnd_hi(f0), h1 = rnd_hi(f1);
        pk.u[e] = (h0 >> 16) | h1;
        float g0 = bits_f32(h0), g1 = bits_f32(h1);
        sq = fmaf(g0, g0, fmaf(g1, g1, sq));
      }
      af[sl] = pk.s8;   // garbage rows are masked by validD below
    }
    sq += __shfl_xor(sq, 16);           // reduce over quads (same doc)
    sq += __shfl_xor(sq, 32);
    float invd = ok ? rsqrtf(sq) : 0.0f;
    float iv[4];
#pragma unroll
    for (int r = 0; r < 4; r++) iv[r] = __shfl(invd, quad * 4 + r);

#pragma unroll
    for (int qt = 0; qt < 3; qt++) {
      floatx4 sim = (floatx4){0.f, 0.f, 0.f, 0.f};
      const unsigned short* qb = qlds + (qt * 16 + li) * 136 + quad * 8;
      sim = __builtin_amdgcn_mfma_f32_16x16x32_bf16(af[0], *(const short8*)(qb), sim, 0, 0, 0);
      sim = __builtin_amdgcn_mfma_f32_16x16x32_bf16(af[1], *(const short8*)(qb + 32), sim, 0, 0, 0);
      sim = __builtin_amdgcn_mfma_f32_16x16x32_bf16(af[2], *(const short8*)(qb + 64), sim, 0, 0, 0);
      sim = __builtin_amdgcn_mfma_f32_16x16x32_bf16(af[3], *(const short8*)(qb + 96), sim, 0, 0, 0);
      float invq = qil[qt * 16 + li];
#pragma unroll
      for (int r = 0; r < 4; r++) {
        if (d0 + quad * 4 + r < validD) {
          float s = sim[r] * (invq * iv[r]);
          // bin 0 (sigma=0.001): exp underflows to 0 unless s ~ 1
          if (s > 0.9868f) {
            float t0 = s - 1.0f;
            accb[qt][0] += __expf(t0 * t0 * -500000.0f);
          }
          // bins 1..10 (sigma=0.1, mu=0.9..-0.9): geometric recurrence
          float y = s - 0.9f;
          float f = __expf(y * y * -50.0f);
          float v = __expf(fmaf(y, -20.0f, -2.0f));
#pragma unroll
          for (int i = 1; i < 11; i++) {
            accb[qt][i] += f;
            f *= v;
            v *= 0.01831563889f;   // e^-4
          }
        }
      }
    }
  }
#pragma unroll
  for (int qt = 0; qt < 3; qt++) {
#pragma unroll
    for (int i = 0; i < 11; i++) {
      float v = accb[qt][i];
      v += __shfl_xor(v, 16);
      v += __shfl_xor(v, 32);
      if (lane < 16) pacc[wave * 528 + (qt * 16 + lane) * 11 + i] = v;
    }
  }
  __syncthreads();
  for (int idx = tid; idx < 528; idx += 256)
    pout[idx] = pacc[idx] + pacc[528 + idx] + pacc[1056 + idx] + pacc[1584 + idx];
}

__global__ __launch_bounds__(256, 4) void k_pool(
    const int* __restrict__ dtok,
    const unsigned short* __restrict__ P,
    const float* __restrict__ bu, const float* __restrict__ bb,
    const float* __restrict__ bt,
    const unsigned short* __restrict__ qvec, const float* __restrict__ qinv,
    float* __restrict__ partial) {
  __shared__ __align__(16) unsigned short qlds[48 * 136];   // 13,056 B
  __shared__ float qil[48];
  __shared__ float pacc[4 * 528];                           // 8,448 B
  int bid = blockIdx.x;
  // LPT: heavy dt=2 first (bid 0..1023), then dt=1, then dt=0.
  int dt = 2 - (bid >> 10);
  int r = bid & 1023;
  int b = r >> 5, chunk = r & 31;
  int tid = threadIdx.x;
  for (int idx = tid; idx < 48 * 32; idx += 256) {
    int row = idx >> 5, kq = (idx & 31) * 4;
    *(uint2*)&qlds[row * 136 + kq] =
        *(const uint2*)(qvec + ((size_t)b * 48 + row) * 128 + kq);
  }
  if (tid < 48) qil[tid] = qinv[b * 48 + tid];
  __syncthreads();
  float* pout = partial + ((size_t)((b * 3 + dt) * 32) + chunk) * 528;
  if (dt == 0)      pool_body<1>(b, chunk, dtok, P, bu, qlds, qil, pacc, pout, tid);
  else if (dt == 1) pool_body<2>(b, chunk, dtok, P, bb, qlds, qil, pacc, pout, tid);
  else              pool_body<3>(b, chunk, dtok, P, bt, qlds, qil, pacc, pout, tid);
}

// ------- fused chunk-reduce + log + query-sum epilogue (one dispatch) -------
__global__ __launch_bounds__(256) void k_finale(const float* __restrict__ partial,
                                                float* __restrict__ out) {
  int idx = blockIdx.x * 256 + threadIdx.x;   // 50688 total
  if (idx >= 32 * 3 * 3 * 11 * 16) return;
  int q = idx & 15;
  int g = idx >> 4;                 // (b,qt,dt,bin), bin fastest
  int bin = g % 11; g /= 11;
  int dt = g % 3; g /= 3;
  int qt = g % 3; int b = g / 3;
  const float* p = partial + ((size_t)(b * 3 + dt) * 32) * 528 + (qt * 16 + q) * 11 + bin;
  float s = 0.f;
#pragma unroll
  for (int c = 0; c < 32; c++) s += p[c * 528];
  float t = (q < 16 - qt) ? 0.01f * logf(fmaxf(s, 1e-10f)) : 0.0f;
#pragma unroll
  for (int off = 1; off < 16; off <<= 1) t += __shfl_xor(t, off);
  if (q == 0) {
    const int p_of[3][3] = {{0, 2, 1}, {3, 5, 6}, {4, 7, 8}};
    out[b * 99 + p_of[qt][dt] * 11 + bin] = t;
  }
}

extern "C" void kernel_launch(void* const* d_in, const int* in_sizes, int n_in,
                              void* d_out, int out_size, void* d_ws, size_t ws_size,
                              hipStream_t stream) {
  const int* qtok = (const int*)d_in[0];
  const int* dtok = (const int*)d_in[1];
  // d_in[2] = batch_semantic: unused by the reference
  const float* wv = (const float*)d_in[3];
  const float* Wu = (const float*)d_in[4];
  const float* bu = (const float*)d_in[5];
  const float* Wb = (const float*)d_in[6];
  const float* bb = (const float*)d_in[7];
  const float* Wt = (const float*)d_in[8];
  const float* bt = (const float*)d_in[9];
  float* out = (float*)d_out;

  // workspace layout (bytes), footprint 148,838,400:
  //   P:       [0, 46,202,880)           30080*768*2   (live: project..pool)
  //   wv_bf:   [46,202,880, 65,454,080)  30080*320*2   (dead after project)
  //   W_bf:    [146,374,656, 146,866,176) 768*320*2    (dead after project)
  //   qvec:    [148,439,040, 148,832,256)
  //   qinv:    [148,832,256, 148,838,400)
  //   partial: [46,202,880, 52,690,944)  3072*528*4    (aliases wv_bf; written
  //            by k_pool after wv_bf is dead)
  char* ws = (char*)d_ws;
  unsigned short* P     = (unsigned short*)(ws);
  unsigned short* wv_bf = (unsigned short*)(ws + 46202880);
  unsigned short* W_bf  = (unsigned short*)(ws + 146374656);
  unsigned short* qvec  = (unsigned short*)(ws + 148439040);
  float* qinv           = (float*)(ws + 148832256);
  float* partial        = (float*)(ws + 46202880);

  k_convert<<<4820, 256, 0, stream>>>(wv, Wu, Wb, Wt, wv_bf, W_bf);
  k_project<<<235 * 6, 256, 0, stream>>>(wv_bf, W_bf, P);
  k_qvec<<<96, 256, 0, stream>>>(qtok, P, bu, bb, bt, qvec, qinv);
  k_pool<<<32 * 96, 256, 0, stream>>>(dtok, P, bu, bb, bt, qvec, qinv, partial);
  k_finale<<<198, 256, 0, stream>>>(partial, out);
}